// Round 5
// baseline (152.767 us; speedup 1.0000x reference)
//
#include <hip/hip_runtime.h>
#include <hip/hip_bf16.h>

// FixedChannelDP via Toeplitz-GEMM on bf16 MFMA 32x32x16.
// y[p,n] = sum_{k=0}^{512} h[k] x[p,n-k]  ('full' conv), out fp32 [2,NOUT,2].
//
// Round 5: PRODUCER/CONSUMER WAVE SPECIALIZATION. Rounds 0-4 all ran at
// ~46-51us = SUM of phase floors (HBM+LDS+MFMA): any structure where compute
// waves also issue global loads eventually blocks on vmcnt under HBM
// contention, and barrier-coupled waves stall together. Fix: wave 0 of each
// block is a pure producer (global load -> cvt bf16 -> ds_write, deep
// ping-pong batches pinned with sched_barrier); waves 1-3 are pure consumers
// (ds_read -> MFMA -> global store; NEVER wait vmcnt). Sync = per-buffer
// monotonic flags in LDS (__hip_atomic, workgroup scope; a workgroup's waves
// are always co-resident -> no dispatch assumptions). No __syncthreads in
// steady state. 256-thr blocks, 76.6 KB LDS -> 2 blocks/CU, grid 512.
//
// Mapping per consumer wave (strip ci, b in [0,34)):
//   D[r][c] += sum_k A_b[r][k] * B_b[k][c],  n = t*3072 + ci*1024 + 32r + c
//   A_b[r][k] = x[n + k + 16 - 16b]                (8 contig -> ds_read_b128)
//   B_b[k][c] = h[16b + c - k - 16] (0 if OOB)     -> tap covered exactly once
// h table: hh[tab][R][j] = h[R-24-j]; row read at R = 16b + cc - 8*half + 8.
// re-part uses xi*(-hi) via one v_xor on the h fragment.

#define NSAMP 4194304
#define LTAPS 513
#define NOUT  (NSAMP + LTAPS - 1)   // 4194816

#define BLK       256
#define NCONS     3                     // consumer waves per block
#define TILE_OUT  3072                  // per pol (3 strips x 1024)
#define HALO      512
#define XELEMS    (TILE_OUT + HALO + 16)   // 3600
#define NB        34
#define HROWS     592
#define GRID      512                   // 2 blocks/CU
#define NT        ((NOUT + TILE_OUT - 1) / TILE_OUT)  // 1366
#define CITERS    15                    // ceil(XELEMS / (64*4)) per comp

typedef __attribute__((ext_vector_type(8)))  short short8;
typedef __attribute__((ext_vector_type(4)))  short short4v;
typedef __attribute__((ext_vector_type(4)))  int   int4v;
typedef __attribute__((ext_vector_type(16))) float float16v;

// XOR swizzle, zero space: folds element bits [6:8] into [3:5]. Bijective in
// each 64-elem block, preserves 8-elem (16 B) units.
__device__ __forceinline__ int xswz(int e) { return e ^ (((e >> 6) & 7) << 3); }
#define XSZ XELEMS   // 3600 elems = 7200 B per plane (16B-aligned)

__device__ __forceinline__ short f2b(float f) {
    __bf16 b = (__bf16)f;
    return __builtin_bit_cast(short, b);
}

__global__ __launch_bounds__(BLK)
void build_h(const float* __restrict__ hr, const float* __restrict__ hi,
             short* __restrict__ hh) {
    int R = blockIdx.x * BLK + threadIdx.x;
    if (R < HROWS) {
        short8 vr, vi;
        #pragma unroll
        for (int j = 0; j < 8; ++j) {
            int idx = R - 24 - j;
            bool ok = (idx >= 0) && (idx < LTAPS);
            vr[j] = f2b(ok ? hr[idx] : 0.0f);
            vi[j] = f2b(ok ? hi[idx] : 0.0f);
        }
        *(short8*)(hh + (size_t)(0 * HROWS + R) * 8) = vr;
        *(short8*)(hh + (size_t)(1 * HROWS + R) * 8) = vi;
    }
}

#define MFMA32(A, B, C) __builtin_amdgcn_mfma_f32_32x32x16_bf16((A), (B), (C), 0, 0, 0)

__device__ __forceinline__ short8 bneg8(short8 v) {
    int4v t = __builtin_bit_cast(int4v, v);
    t ^= (int4v){(int)0x80008000, (int)0x80008000, (int)0x80008000, (int)0x80008000};
    return __builtin_bit_cast(short8, t);
}

__global__ __launch_bounds__(BLK, 2)
void fir_pc(const float* __restrict__ txr_all, const float* __restrict__ txi_all,
            const short* __restrict__ hh, float2* __restrict__ out) {
    const int bid  = blockIdx.x;
    const int tid  = threadIdx.x;
    const int lane = tid & 63;
    const int wave = tid >> 6;

    // x tiles double-buffered: [buf][0]=xr p0,[1]=xi p0,[2]=xr p1,[3]=xi p1
    __shared__ __align__(16) short xs[2][4][XSZ];     // 57,600 B
    __shared__ __align__(16) short hl[2 * HROWS * 8]; // 18,944 B
    __shared__ int rdy[2];    // latest staged g+1 per buffer
    __shared__ int done[2];   // cumulative consumer-finish count per buffer

    if (tid < 2) { rdy[tid] = 0; done[tid] = 0; }
    __syncthreads();   // only barrier in the kernel (flag init)

    // producer wave index depends on block parity: on a CU hosting blocks of
    // opposite parity, producers land on different SIMDs.
    const int pwave = (bid & 1) ? 3 : 0;

    if (wave == pwave) {
        // ======================= PRODUCER =======================
        // h table -> LDS once (before rdy[0] is released)
        {
            const int4* src = (const int4*)hh;
            int4* dst = (int4*)hl;
            #pragma unroll
            for (int it = 0; it < 19; ++it) {
                int idx = lane + it * 64;
                if (idx < 2 * HROWS) dst[idx] = src[idx];
            }
        }

        for (int t = bid, g = 0; t < NT; t += GRID, ++g) {
            const int buf = g & 1;
            if (g >= 2) {   // wait until all consumers finished this buffer
                const int need = NCONS * (g >> 1);
                while (__hip_atomic_load(&done[buf], __ATOMIC_ACQUIRE,
                                         __HIP_MEMORY_SCOPE_WORKGROUP) < need)
                    __builtin_amdgcn_s_sleep(1);
            }

            if (t != 0 && t != NT - 1) {
                // ---- fast path: unconditional float4 loads, ping-pong batches ----
                const long gb = (long)t * TILE_OUT - HALO;
                const float* cp0 = txr_all + gb;
                const float* cp1 = txi_all + gb;
                const float* cp2 = txr_all + (size_t)NSAMP + gb;
                const float* cp3 = txi_all + (size_t)NSAMP + gb;
                const float* cps[4] = { cp0, cp1, cp2, cp3 };
                float4 vb[2][CITERS];

                // L(c): issue comp-c loads into slot c&1; W(c): cvt+ds_write
                #define PLOAD(c)                                               \
                    _Pragma("unroll")                                          \
                    for (int j = 0; j < CITERS; ++j) {                         \
                        int e = (lane + 64 * j) * 4;                           \
                        if (e < XELEMS)                                        \
                            vb[(c) & 1][j] = *(const float4*)(cps[(c)] + e);   \
                    }
                #define PWRITE(c)                                              \
                    _Pragma("unroll")                                          \
                    for (int j = 0; j < CITERS; ++j) {                         \
                        int e = (lane + 64 * j) * 4;                           \
                        if (e < XELEMS) {                                      \
                            float4 v = vb[(c) & 1][j];                         \
                            short4v s = { f2b(v.x), f2b(v.y),                  \
                                          f2b(v.z), f2b(v.w) };                \
                            *(short4v*)(&xs[buf][(c)][xswz(e)]) = s;           \
                        }                                                      \
                    }
                PLOAD(0);
                __builtin_amdgcn_sched_barrier(0);
                PLOAD(1);
                __builtin_amdgcn_sched_barrier(0);
                PWRITE(0);
                __builtin_amdgcn_sched_barrier(0);
                PLOAD(2);
                __builtin_amdgcn_sched_barrier(0);
                PWRITE(1);
                __builtin_amdgcn_sched_barrier(0);
                PLOAD(3);
                __builtin_amdgcn_sched_barrier(0);
                PWRITE(2);
                __builtin_amdgcn_sched_barrier(0);
                PWRITE(3);
                #undef PLOAD
                #undef PWRITE
            } else {
                // ---- slow path (t=0, t=NT-1): per-element clamped staging ----
                const int N0 = t * TILE_OUT;
                for (int c = 0; c < 4; ++c) {
                    const int p = c >> 1;
                    const float* xg = ((c & 1) ? txi_all : txr_all) + (size_t)p * NSAMP;
                    for (int j = 0; j < CITERS; ++j) {
                        int e = (lane + 64 * j) * 4;
                        if (e < XELEMS) {
                            int g0 = N0 - HALO + e;
                            float v0, v1, v2, v3;
                            if (g0 >= 0 && g0 + 3 < NSAMP) {
                                float4 fv = *(const float4*)(xg + g0);
                                v0 = fv.x; v1 = fv.y; v2 = fv.z; v3 = fv.w;
                            } else {
                                int c0 = min(max(g0 + 0, 0), NSAMP - 1);
                                int c1 = min(max(g0 + 1, 0), NSAMP - 1);
                                int c2 = min(max(g0 + 2, 0), NSAMP - 1);
                                int c3 = min(max(g0 + 3, 0), NSAMP - 1);
                                v0 = (g0 + 0 >= 0 && g0 + 0 < NSAMP) ? xg[c0] : 0.0f;
                                v1 = (g0 + 1 >= 0 && g0 + 1 < NSAMP) ? xg[c1] : 0.0f;
                                v2 = (g0 + 2 >= 0 && g0 + 2 < NSAMP) ? xg[c2] : 0.0f;
                                v3 = (g0 + 3 >= 0 && g0 + 3 < NSAMP) ? xg[c3] : 0.0f;
                            }
                            short4v s = { f2b(v0), f2b(v1), f2b(v2), f2b(v3) };
                            *(short4v*)(&xs[buf][c][xswz(e)]) = s;
                        }
                    }
                }
            }

            // make ds_writes visible, then release the buffer to consumers
            asm volatile("s_waitcnt lgkmcnt(0)" ::: "memory");
            if (lane == 0)
                __hip_atomic_store(&rdy[buf], g + 1, __ATOMIC_RELEASE,
                                   __HIP_MEMORY_SCOPE_WORKGROUP);
        }
    } else {
        // ======================= CONSUMER =======================
        const int ci   = (wave < pwave) ? wave : wave - 1;   // 0..2
        const int cc   = lane & 31;
        const int half = lane >> 5;
        const short* hp0  = hl + (size_t)(cc - 8 * half + 8) * 8;
        const int   ebase = HALO + ci * 1024 + 32 * cc + 8 * half + 16;

        for (int t = bid, g = 0; t < NT; t += GRID, ++g) {
            const int buf = g & 1;
            while (__hip_atomic_load(&rdy[buf], __ATOMIC_ACQUIRE,
                                     __HIP_MEMORY_SCOPE_WORKGROUP) < g + 1)
                __builtin_amdgcn_s_sleep(1);

            const int nw = t * TILE_OUT + ci * 1024;
            if (nw < NOUT) {
                float16v zero = {0.f,0.f,0.f,0.f,0.f,0.f,0.f,0.f,
                                 0.f,0.f,0.f,0.f,0.f,0.f,0.f,0.f};
                float16v acc_re0 = zero, acc_im0 = zero;
                float16v acc_re1 = zero, acc_im1 = zero;
                const short* xb = &xs[buf][0][0];

                #pragma unroll
                for (int b = 0; b < NB; ++b) {
                    int ls = xswz(ebase - 16 * b);
                    short8 fxr0 = *(const short8*)(xb + ls);
                    short8 fxi0 = *(const short8*)(xb + XSZ + ls);
                    short8 fxr1 = *(const short8*)(xb + 2 * XSZ + ls);
                    short8 fxi1 = *(const short8*)(xb + 3 * XSZ + ls);
                    const short* hp = hp0 + (size_t)(16 * b) * 8;
                    short8 fhr = *(const short8*)(hp);
                    short8 fhi = *(const short8*)(hp + (size_t)HROWS * 8);

                    short8 fnhi = bneg8(fhi);   // re-part: xi * (-hi)
                    acc_re0 = MFMA32(fxr0, fhr,  acc_re0);
                    acc_im0 = MFMA32(fxi0, fhr,  acc_im0);
                    acc_re1 = MFMA32(fxr1, fhr,  acc_re1);
                    acc_im1 = MFMA32(fxi1, fhr,  acc_im1);
                    acc_re0 = MFMA32(fxi0, fnhi, acc_re0);
                    acc_im0 = MFMA32(fxr0, fhi,  acc_im0);
                    acc_re1 = MFMA32(fxi1, fnhi, acc_re1);
                    acc_im1 = MFMA32(fxr1, fhi,  acc_im1);
                }

                // epilogue: D col = cc, row = (reg&3) + 8*(reg>>2) + 4*half.
                // Fire-and-forget stores: consumer never waits vmcnt.
                float2* __restrict__ op0 = out;
                float2* __restrict__ op1 = out + (size_t)NOUT;
                #pragma unroll
                for (int v = 0; v < 16; ++v) {
                    int row = (v & 3) + 8 * (v >> 2) + 4 * half;
                    int n = nw + 32 * row + cc;
                    if (n < NOUT) {
                        op0[n] = make_float2(acc_re0[v], acc_im0[v]);
                        op1[n] = make_float2(acc_re1[v], acc_im1[v]);
                    }
                }
            }

            if (lane == 0)
                __hip_atomic_fetch_add(&done[buf], 1, __ATOMIC_RELEASE,
                                       __HIP_MEMORY_SCOPE_WORKGROUP);
        }
    }
}

extern "C" void kernel_launch(void* const* d_in, const int* in_sizes, int n_in,
                              void* d_out, int out_size, void* d_ws, size_t ws_size,
                              hipStream_t stream) {
    const float* txr = (const float*)d_in[0];
    const float* txi = (const float*)d_in[1];
    const float* hr  = (const float*)d_in[2];
    const float* hi  = (const float*)d_in[3];
    float2* out = (float2*)d_out;
    short* hh = (short*)d_ws;   // 2 * 592 * 8 bf16 ≈ 19 KB

    build_h<<<dim3((HROWS + BLK - 1) / BLK), BLK, 0, stream>>>(hr, hi, hh);

    fir_pc<<<dim3(GRID), BLK, 0, stream>>>(txr, txi, hh, out);
}

// Round 6
// 149.565 us; speedup vs baseline: 1.0214x; 1.0214x over previous
//
#include <hip/hip_runtime.h>
#include <hip/hip_bf16.h>

// FixedChannelDP via Toeplitz-GEMM on bf16 MFMA 32x32x16.
// y[p,n] = sum_{k=0}^{512} h[k] x[p,n-k]  ('full' conv), out fp32 [2,NOUT,2].
//
// Round 6: round-1's proven compute mapping (pad swizzle, 295K conflicts;
// both pols per wave sharing h frags) + PERSISTENT BLOCKS with a cross-tile
// register pipeline:
//   - grid 256 = 1 block/CU, 4 waves, double-buffered x in LDS (111 KB).
//   - iteration g: issue tile g+1's 20 unconditional float4 loads, then a
//     memory-clobber asm (pins the loads: MachineSink can't cross it, and it
//     uses no values so no waitcnt is forced), then compute tile g entirely
//     from LDS (~9k cyc), then cvt+ds_write the staged regs (vmcnt wait here
//     is one compute-phase old => free), then fire-and-forget stores, then
//     lgkmcnt(0)+s_barrier. Stage-HBM and store-HBM overlap compute.
//   - edge tiles (0, 1023, 1024) use the slow clamped path.
//
// Mapping per wave (strip = wave, b in [0,34)):
//   D[r][c] += sum_k A_b[r][k] * B_b[k][c],  n = N0 + wave*1024 + 32r + c
//   A_b[r][k] = x[n + k + 16 - 16b]                (8 contig -> ds_read_b128)
//   B_b[k][c] = h[16b + c - k - 16] (0 if OOB)     -> tap covered exactly once
// h table: hh[tab][R][j] = h[R-24-j]; row read at R = 16b + cc - 8*half + 8;
// rows >= 544 all-zero (b+1 prefetch safe).  re-part uses xi*(-hi) via v_xor.

#define NSAMP 4194304
#define LTAPS 513
#define NOUT  (NSAMP + LTAPS - 1)   // 4194816

#define BLK       256
#define WAVE_OUT  1024                  // one 32x32 D-tile strip per wave
#define BLOCK_OUT 4096                  // per pol (4 strips x 4 waves, both pols)
#define HALO      512
#define XELEMS    (BLOCK_OUT + HALO + 16)   // 4624
#define EMAX      (XELEMS - 4)              // 4620: clamp for unconditional loads
#define NB        34
#define HROWS     592
#define GRID      256                   // persistent, 1 block/CU
#define NT        ((NOUT + BLOCK_OUT - 1) / BLOCK_OUT)  // 1025
#define SITER     5                     // float4 per plane per thread

typedef __attribute__((ext_vector_type(8)))  short short8;
typedef __attribute__((ext_vector_type(4)))  short short4v;
typedef __attribute__((ext_vector_type(4)))  int   int4v;
typedef __attribute__((ext_vector_type(16))) float float16v;

// Pad swizzle (+8 elems per 32): A-frag b128 reads hit all 32 banks.
// Proven in rounds 0/1: 295K conflict cycles (vs 2.23M for XOR variant).
__device__ __forceinline__ int xswz(int e) { return e + ((e >> 5) << 3); }
#define XSZ 5776   // xswz(4620)+4 = 5776 (16B aligned)

__device__ __forceinline__ short f2b(float f) {
    __bf16 b = (__bf16)f;
    return __builtin_bit_cast(short, b);
}

__global__ __launch_bounds__(BLK)
void build_h(const float* __restrict__ hr, const float* __restrict__ hi,
             short* __restrict__ hh) {
    int R = blockIdx.x * BLK + threadIdx.x;
    if (R < HROWS) {
        short8 vr, vi;
        #pragma unroll
        for (int j = 0; j < 8; ++j) {
            int idx = R - 24 - j;
            bool ok = (idx >= 0) && (idx < LTAPS);
            vr[j] = f2b(ok ? hr[idx] : 0.0f);
            vi[j] = f2b(ok ? hi[idx] : 0.0f);
        }
        *(short8*)(hh + (size_t)(0 * HROWS + R) * 8) = vr;
        *(short8*)(hh + (size_t)(1 * HROWS + R) * 8) = vi;
    }
}

#define MFMA32(A, B, C) __builtin_amdgcn_mfma_f32_32x32x16_bf16((A), (B), (C), 0, 0, 0)

__device__ __forceinline__ short8 bneg8(short8 v) {
    int4v t = __builtin_bit_cast(int4v, v);
    t ^= (int4v){(int)0x80008000, (int)0x80008000, (int)0x80008000, (int)0x80008000};
    return __builtin_bit_cast(short8, t);
}

__device__ __forceinline__ bool tile_edge(int t) { return (t == 0) || (t >= 1023); }

__global__ __launch_bounds__(BLK, 1)
void fir_pipe(const float* __restrict__ txr_all, const float* __restrict__ txi_all,
              const short* __restrict__ hh, float2* __restrict__ out) {
    const int bid = blockIdx.x;
    const int tid = threadIdx.x;

    // double-buffered x tiles: [buf][0]=xr p0,[1]=xi p0,[2]=xr p1,[3]=xi p1
    __shared__ __align__(16) short xs[2][4][XSZ];     //  92,416 B
    __shared__ __align__(16) short hl[2 * HROWS * 8]; //  18,944 B (tot 111,360)

    // ---- h table -> LDS once ----
    {
        const int4* src = (const int4*)hh;
        int4* dst = (int4*)hl;
        #pragma unroll
        for (int it = 0; it < 5; ++it) {
            int idx = tid + it * BLK;
            if (idx < 2 * HROWS / 2 * 2 * 8 / 8) {}   // no-op guard elision helper
            if (idx < (2 * HROWS * 8) / 8) dst[idx] = src[idx];
        }
    }

    // slow clamped staging (prologue + edge tiles)
    auto stage_slow = [&](int t, int buf) {
        const int N0 = t * BLOCK_OUT;
        #pragma unroll
        for (int p = 0; p < 2; ++p) {
            const float* __restrict__ xr_g = txr_all + (size_t)p * NSAMP;
            const float* __restrict__ xi_g = txi_all + (size_t)p * NSAMP;
            for (int it = 0; it < SITER; ++it) {
                int e = (tid + it * BLK) * 4;
                if (e < XELEMS) {
                    int g = N0 - HALO + e;
                    float r0, r1, r2, r3, i0, i1, i2, i3;
                    if (g >= 0 && g + 3 < NSAMP) {
                        float4 frv = *(const float4*)(xr_g + g);
                        float4 fiv = *(const float4*)(xi_g + g);
                        r0 = frv.x; r1 = frv.y; r2 = frv.z; r3 = frv.w;
                        i0 = fiv.x; i1 = fiv.y; i2 = fiv.z; i3 = fiv.w;
                    } else {
                        int gc0 = min(max(g + 0, 0), NSAMP - 1);
                        int gc1 = min(max(g + 1, 0), NSAMP - 1);
                        int gc2 = min(max(g + 2, 0), NSAMP - 1);
                        int gc3 = min(max(g + 3, 0), NSAMP - 1);
                        r0 = (g + 0 >= 0 && g + 0 < NSAMP) ? xr_g[gc0] : 0.0f;
                        r1 = (g + 1 >= 0 && g + 1 < NSAMP) ? xr_g[gc1] : 0.0f;
                        r2 = (g + 2 >= 0 && g + 2 < NSAMP) ? xr_g[gc2] : 0.0f;
                        r3 = (g + 3 >= 0 && g + 3 < NSAMP) ? xr_g[gc3] : 0.0f;
                        i0 = (g + 0 >= 0 && g + 0 < NSAMP) ? xi_g[gc0] : 0.0f;
                        i1 = (g + 1 >= 0 && g + 1 < NSAMP) ? xi_g[gc1] : 0.0f;
                        i2 = (g + 2 >= 0 && g + 2 < NSAMP) ? xi_g[gc2] : 0.0f;
                        i3 = (g + 3 >= 0 && g + 3 < NSAMP) ? xi_g[gc3] : 0.0f;
                    }
                    int ls = xswz(e);
                    short4v vr = { f2b(r0), f2b(r1), f2b(r2), f2b(r3) };
                    short4v vi = { f2b(i0), f2b(i1), f2b(i2), f2b(i3) };
                    *(short4v*)(&xs[buf][2 * p + 0][ls]) = vr;
                    *(short4v*)(&xs[buf][2 * p + 1][ls]) = vi;
                }
            }
        }
    };

    const int lane = tid & 63;
    const int wave = tid >> 6;
    const int cc   = lane & 31;     // A row r / B col c / D col
    const int half = lane >> 5;
    const short* hp0  = hl + (size_t)(cc - 8 * half + 8) * 8;
    const int   ebase = HALO + wave * WAVE_OUT + 32 * cc + 8 * half + 16;

    // ---- prologue: stage own first tile into buf 0 ----
    stage_slow(bid, 0);
    __syncthreads();

    int cur = 0;
    for (int t = bid; t < NT; t += GRID) {
        const int  tn   = t + GRID;
        const bool pipe = (tn < NT) && !tile_edge(tn);
        const int  nw   = t * BLOCK_OUT + wave * WAVE_OUT;
        const bool did  = (nw < NOUT);

        // ---- (1) issue next tile's 20 unconditional clamped loads ----
        float4 ld0[SITER], ld1[SITER], ld2[SITER], ld3[SITER];
        if (pipe) {
            const long gb  = (long)tn * BLOCK_OUT - HALO;
            const float* g0 = txr_all + gb;                    // p0 re
            const float* g1 = txi_all + gb;                    // p0 im
            const float* g2 = txr_all + (size_t)NSAMP + gb;    // p1 re
            const float* g3 = txi_all + (size_t)NSAMP + gb;    // p1 im
            #pragma unroll
            for (int it = 0; it < SITER; ++it) {
                int e = min((tid + it * BLK) * 4, EMAX);
                ld0[it] = *(const float4*)(g0 + e);
                ld1[it] = *(const float4*)(g1 + e);
                ld2[it] = *(const float4*)(g2 + e);
                ld3[it] = *(const float4*)(g3 + e);
            }
        }
        // pin the loads here: memory-clobber blocks sinking, uses no values
        asm volatile("" ::: "memory");
        __builtin_amdgcn_sched_barrier(0);

        // ---- (2) compute tile t from xs[cur] (all-LDS inner loop) ----
        float16v zero = {0.f,0.f,0.f,0.f,0.f,0.f,0.f,0.f,0.f,0.f,0.f,0.f,0.f,0.f,0.f,0.f};
        float16v acc_re0 = zero, acc_im0 = zero, acc_re1 = zero, acc_im1 = zero;
        if (did) {
            const short* xb = &xs[cur][0][0];
            int ls0 = xswz(ebase);
            short8 fxr0 = *(const short8*)(xb + ls0);
            short8 fxi0 = *(const short8*)(xb + XSZ + ls0);
            short8 fxr1 = *(const short8*)(xb + 2 * XSZ + ls0);
            short8 fxi1 = *(const short8*)(xb + 3 * XSZ + ls0);
            short8 fhr  = *(const short8*)(hp0);
            short8 fhi  = *(const short8*)(hp0 + (size_t)HROWS * 8);

            #pragma unroll 2
            for (int b = 0; b < NB; ++b) {
                int en = ebase - 16 * (b + 1);
                en = en < 0 ? 0 : en;         // b=NB-1 prefetch: clamp (unused)
                int lsn = xswz(en);
                short8 nxr0 = *(const short8*)(xb + lsn);
                short8 nxi0 = *(const short8*)(xb + XSZ + lsn);
                short8 nxr1 = *(const short8*)(xb + 2 * XSZ + lsn);
                short8 nxi1 = *(const short8*)(xb + 3 * XSZ + lsn);
                const short* hn = hp0 + (size_t)(16 * (b + 1)) * 8;
                short8 nhr = *(const short8*)(hn);
                short8 nhi = *(const short8*)(hn + (size_t)HROWS * 8);

                short8 fnhi = bneg8(fhi);     // re-part: xi * (-hi)
                acc_re0 = MFMA32(fxr0, fhr,  acc_re0);
                acc_im0 = MFMA32(fxi0, fhr,  acc_im0);
                acc_re1 = MFMA32(fxr1, fhr,  acc_re1);
                acc_im1 = MFMA32(fxi1, fhr,  acc_im1);
                acc_re0 = MFMA32(fxi0, fnhi, acc_re0);
                acc_im0 = MFMA32(fxr0, fhi,  acc_im0);
                acc_re1 = MFMA32(fxi1, fnhi, acc_re1);
                acc_im1 = MFMA32(fxr1, fhi,  acc_im1);

                fxr0 = nxr0; fxi0 = nxi0; fxr1 = nxr1; fxi1 = nxi1;
                fhr  = nhr;  fhi  = nhi;
            }
        }

        // ---- (3) cvt + ds_write staged tile into xs[cur^1] ----
        // (vmcnt wait for the loads lands here, one compute-phase old => free)
        if (pipe) {
            #pragma unroll
            for (int it = 0; it < SITER; ++it) {
                int e  = min((tid + it * BLK) * 4, EMAX);
                int ls = xswz(e);
                float4 v0 = ld0[it], v1 = ld1[it], v2 = ld2[it], v3 = ld3[it];
                short4v s0 = { f2b(v0.x), f2b(v0.y), f2b(v0.z), f2b(v0.w) };
                short4v s1 = { f2b(v1.x), f2b(v1.y), f2b(v1.z), f2b(v1.w) };
                short4v s2 = { f2b(v2.x), f2b(v2.y), f2b(v2.z), f2b(v2.w) };
                short4v s3 = { f2b(v3.x), f2b(v3.y), f2b(v3.z), f2b(v3.w) };
                *(short4v*)(&xs[cur ^ 1][0][ls]) = s0;
                *(short4v*)(&xs[cur ^ 1][1][ls]) = s1;
                *(short4v*)(&xs[cur ^ 1][2][ls]) = s2;
                *(short4v*)(&xs[cur ^ 1][3][ls]) = s3;
            }
        } else if (tn < NT) {
            stage_slow(tn, cur ^ 1);          // edge tiles 1023/1024
        }

        // ---- (4) epilogue stores: fire-and-forget, drain under barrier ----
        if (did) {
            float2* __restrict__ op0 = out;
            float2* __restrict__ op1 = out + (size_t)NOUT;
            #pragma unroll
            for (int v = 0; v < 16; ++v) {
                int row = (v & 3) + 8 * (v >> 2) + 4 * half;
                int n = nw + 32 * row + cc;
                if (n < NOUT) {
                    op0[n] = make_float2(acc_re0[v], acc_im0[v]);
                    op1[n] = make_float2(acc_re1[v], acc_im1[v]);
                }
            }
        }

        // ---- (5) one barrier per tile: LDS drain only, no vmcnt(0) ----
        asm volatile("s_waitcnt lgkmcnt(0)" ::: "memory");
        __builtin_amdgcn_s_barrier();
        __builtin_amdgcn_sched_barrier(0);
        cur ^= 1;
    }
}

extern "C" void kernel_launch(void* const* d_in, const int* in_sizes, int n_in,
                              void* d_out, int out_size, void* d_ws, size_t ws_size,
                              hipStream_t stream) {
    const float* txr = (const float*)d_in[0];
    const float* txi = (const float*)d_in[1];
    const float* hr  = (const float*)d_in[2];
    const float* hi  = (const float*)d_in[3];
    float2* out = (float2*)d_out;
    short* hh = (short*)d_ws;   // 2 * 592 * 8 bf16 ≈ 19 KB

    build_h<<<dim3((HROWS + BLK - 1) / BLK), BLK, 0, stream>>>(hr, hi, hh);

    fir_pipe<<<dim3(GRID), BLK, 0, stream>>>(txr, txi, hh, out);
}

// Round 7
// 147.000 us; speedup vs baseline: 1.0392x; 1.0175x over previous
//
#include <hip/hip_runtime.h>
#include <hip/hip_bf16.h>

// FixedChannelDP via Toeplitz-GEMM on bf16 MFMA 32x32x16.
// y[p,n] = sum_{k=0}^{512} h[k] x[p,n-k]  ('full' conv), out fp32 [2,NOUT,2].
//
// Round 7: CROSS-BLOCK PHASE STAGGER. Rounds 0-6 showed (a) wall time ==
// SUM of phase floors (stage-HBM + compute + write ~= 47us) because all
// co-resident blocks run the same phase in lockstep (HBM contention is a
// phase-synchronizing attractor), and (b) intra-block overlap fails (the
// compiler sinks monolithic prefetches; interleaved rings die of latency at
// low occupancy). Fix: keep round-2's PROVEN serial stage/compute verbatim,
// put 2 blocks on each CU (74 KB LDS, x double-buffered, h stays in L1-hot
// global), and ANTI-PHASE the pair by block id:
//   even   : stage T0 | bar | compute T0 | stage T1 | bar | compute T1
//   stagger: stage T0 | stage T1 | bar | compute T0 | compute T1
// While one block computes (MFMA+LDS pipes) its partner stages (HBM pipe).
// Barriers are lgkmcnt-only (no vmcnt(0) store drain). True roofline:
// max(HBM ~17us, MFMA ~15us) ~= 18-22us.
//
// Mapping per wave (strip = wave, b in [0,34)):
//   D[r][c] += sum_k A_b[r][k] * B_b[k][c],  n = N0 + wave*1024 + 32r + c
//   A_b[r][k] = x[n + k + 16 - 16b]                (8 contig -> ds_read_b128)
//   B_b[k][c] = h[16b + c - k - 16] (0 if OOB)     -> tap covered exactly once
// h table (global ws, L1-hot 19KB): hh[tab][R][j] = h[R-24-j]; row read at
// R = 16b + cc - 8*half + 8; rows >= 544 all-zero (b+1 prefetch safe).
// re-part uses xi*(-hi) via one v_xor on the h fragment.

#define NSAMP 4194304
#define LTAPS 513
#define NOUT  (NSAMP + LTAPS - 1)   // 4194816

#define BLK       256
#define WAVE_OUT  1024                  // one 32x32 D-tile strip per wave
#define BLOCK_OUT 4096                  // per pol (4 strips x 4 waves, both pols)
#define HALO      512
#define XELEMS    (BLOCK_OUT + HALO + 16)   // 4624
#define NB        34
#define HROWS     592
#define GRID      512                   // 2 blocks/CU
#define RUNT      1024                  // runt tile (512 outputs), block 511
#define SITER     5

typedef __attribute__((ext_vector_type(8)))  short short8;
typedef __attribute__((ext_vector_type(4)))  short short4v;
typedef __attribute__((ext_vector_type(4)))  int   int4v;
typedef __attribute__((ext_vector_type(16))) float float16v;

// XOR swizzle, zero space: folds element bits [6:8] into [3:5]. Bijective in
// each 64-elem block, preserves 8-elem (16 B) units.
__device__ __forceinline__ int xswz(int e) { return e ^ (((e >> 6) & 7) << 3); }
#define XSZ XELEMS

__device__ __forceinline__ short f2b(float f) {
    __bf16 b = (__bf16)f;
    return __builtin_bit_cast(short, b);
}

__global__ __launch_bounds__(BLK)
void build_h(const float* __restrict__ hr, const float* __restrict__ hi,
             short* __restrict__ hh) {
    int R = blockIdx.x * BLK + threadIdx.x;
    if (R < HROWS) {
        short8 vr, vi;
        #pragma unroll
        for (int j = 0; j < 8; ++j) {
            int idx = R - 24 - j;
            bool ok = (idx >= 0) && (idx < LTAPS);
            vr[j] = f2b(ok ? hr[idx] : 0.0f);
            vi[j] = f2b(ok ? hi[idx] : 0.0f);
        }
        *(short8*)(hh + (size_t)(0 * HROWS + R) * 8) = vr;
        *(short8*)(hh + (size_t)(1 * HROWS + R) * 8) = vi;
    }
}

#define MFMA32(A, B, C) __builtin_amdgcn_mfma_f32_32x32x16_bf16((A), (B), (C), 0, 0, 0)

__device__ __forceinline__ short8 bneg8(short8 v) {
    int4v t = __builtin_bit_cast(int4v, v);
    t ^= (int4v){(int)0x80008000, (int)0x80008000, (int)0x80008000, (int)0x80008000};
    return __builtin_bit_cast(short8, t);
}

// lgkm-only barrier: staged ds_writes visible, no vmcnt(0) store drain.
#define BAR()  do {                                         \
        asm volatile("s_waitcnt lgkmcnt(0)" ::: "memory");  \
        __builtin_amdgcn_s_barrier();                       \
        __builtin_amdgcn_sched_barrier(0);                  \
    } while (0)

__device__ __forceinline__ void stage_tile(
        const float* __restrict__ txr_all, const float* __restrict__ txi_all,
        short (*__restrict__ xsb)[XSZ], int t, int tid) {
    const int N0 = t * BLOCK_OUT;
    const bool edge = (t == 0) || (t >= 1023);   // 1023 peeks past NSAMP; 1024 runt
    if (!edge) {
        const long gb = (long)N0 - HALO;
        #pragma unroll
        for (int p = 0; p < 2; ++p) {
            const float* __restrict__ xr_g = txr_all + (size_t)p * NSAMP + gb;
            const float* __restrict__ xi_g = txi_all + (size_t)p * NSAMP + gb;
            #pragma unroll
            for (int it = 0; it < SITER; ++it) {
                int e = (tid + it * BLK) * 4;
                if (e < XELEMS) {
                    float4 r = *(const float4*)(xr_g + e);
                    float4 i = *(const float4*)(xi_g + e);
                    int ls = xswz(e);
                    short4v vr = { f2b(r.x), f2b(r.y), f2b(r.z), f2b(r.w) };
                    short4v vi = { f2b(i.x), f2b(i.y), f2b(i.z), f2b(i.w) };
                    *(short4v*)(&xsb[2 * p + 0][ls]) = vr;
                    *(short4v*)(&xsb[2 * p + 1][ls]) = vi;
                }
            }
        }
    } else {
        for (int p = 0; p < 2; ++p) {
            const float* __restrict__ xr_g = txr_all + (size_t)p * NSAMP;
            const float* __restrict__ xi_g = txi_all + (size_t)p * NSAMP;
            for (int it = 0; it < SITER; ++it) {
                int e = (tid + it * BLK) * 4;
                if (e < XELEMS) {
                    int g = N0 - HALO + e;
                    float r0, r1, r2, r3, i0, i1, i2, i3;
                    if (g >= 0 && g + 3 < NSAMP) {
                        float4 fr = *(const float4*)(xr_g + g);
                        float4 fi = *(const float4*)(xi_g + g);
                        r0 = fr.x; r1 = fr.y; r2 = fr.z; r3 = fr.w;
                        i0 = fi.x; i1 = fi.y; i2 = fi.z; i3 = fi.w;
                    } else {
                        int gc0 = min(max(g + 0, 0), NSAMP - 1);
                        int gc1 = min(max(g + 1, 0), NSAMP - 1);
                        int gc2 = min(max(g + 2, 0), NSAMP - 1);
                        int gc3 = min(max(g + 3, 0), NSAMP - 1);
                        r0 = (g + 0 >= 0 && g + 0 < NSAMP) ? xr_g[gc0] : 0.0f;
                        r1 = (g + 1 >= 0 && g + 1 < NSAMP) ? xr_g[gc1] : 0.0f;
                        r2 = (g + 2 >= 0 && g + 2 < NSAMP) ? xr_g[gc2] : 0.0f;
                        r3 = (g + 3 >= 0 && g + 3 < NSAMP) ? xr_g[gc3] : 0.0f;
                        i0 = (g + 0 >= 0 && g + 0 < NSAMP) ? xi_g[gc0] : 0.0f;
                        i1 = (g + 1 >= 0 && g + 1 < NSAMP) ? xi_g[gc1] : 0.0f;
                        i2 = (g + 2 >= 0 && g + 2 < NSAMP) ? xi_g[gc2] : 0.0f;
                        i3 = (g + 3 >= 0 && g + 3 < NSAMP) ? xi_g[gc3] : 0.0f;
                    }
                    int ls = xswz(e);
                    short4v vr = { f2b(r0), f2b(r1), f2b(r2), f2b(r3) };
                    short4v vi = { f2b(i0), f2b(i1), f2b(i2), f2b(i3) };
                    *(short4v*)(&xsb[2 * p + 0][ls]) = vr;
                    *(short4v*)(&xsb[2 * p + 1][ls]) = vi;
                }
            }
        }
    }
}

__device__ __forceinline__ void compute_tile(
        const short* __restrict__ hh, float2* __restrict__ out,
        const short* __restrict__ xb, int t, int lane, int wave) {
    const int nw = t * BLOCK_OUT + wave * WAVE_OUT;
    if (nw >= NOUT) return;   // runt tile: waves 1-3 idle (no barrier inside)

    const int cc   = lane & 31;
    const int half = lane >> 5;
    const short* hp0  = hh + (size_t)(cc - 8 * half + 8) * 8;
    const int   ebase = HALO + wave * WAVE_OUT + 32 * cc + 8 * half + 16;

    float16v zero = {0.f,0.f,0.f,0.f,0.f,0.f,0.f,0.f,0.f,0.f,0.f,0.f,0.f,0.f,0.f,0.f};
    float16v acc_re0 = zero, acc_im0 = zero, acc_re1 = zero, acc_im1 = zero;

    // prologue: fragments for b=0
    int ls0 = xswz(ebase);
    short8 fxr0 = *(const short8*)(xb + ls0);
    short8 fxi0 = *(const short8*)(xb + XSZ + ls0);
    short8 fxr1 = *(const short8*)(xb + 2 * XSZ + ls0);
    short8 fxi1 = *(const short8*)(xb + 3 * XSZ + ls0);
    short8 fhr  = *(const short8*)(hp0);
    short8 fhi  = *(const short8*)(hp0 + (size_t)HROWS * 8);

    #pragma unroll 2
    for (int b = 0; b < NB; ++b) {
        // prefetch b+1 operands before b's MFMAs
        int en = ebase - 16 * (b + 1);
        en = en < 0 ? 0 : en;           // b=NB-1: clamp (values unused)
        int lsn = xswz(en);
        short8 nxr0 = *(const short8*)(xb + lsn);
        short8 nxi0 = *(const short8*)(xb + XSZ + lsn);
        short8 nxr1 = *(const short8*)(xb + 2 * XSZ + lsn);
        short8 nxi1 = *(const short8*)(xb + 3 * XSZ + lsn);
        const short* hn = hp0 + (size_t)(16 * (b + 1)) * 8;
        short8 nhr = *(const short8*)(hn);
        short8 nhi = *(const short8*)(hn + (size_t)HROWS * 8);

        short8 fnhi = bneg8(fhi);       // re-part: xi * (-hi)
        acc_re0 = MFMA32(fxr0, fhr,  acc_re0);
        acc_im0 = MFMA32(fxi0, fhr,  acc_im0);
        acc_re1 = MFMA32(fxr1, fhr,  acc_re1);
        acc_im1 = MFMA32(fxi1, fhr,  acc_im1);
        acc_re0 = MFMA32(fxi0, fnhi, acc_re0);
        acc_im0 = MFMA32(fxr0, fhi,  acc_im0);
        acc_re1 = MFMA32(fxi1, fnhi, acc_re1);
        acc_im1 = MFMA32(fxr1, fhi,  acc_im1);

        fxr0 = nxr0; fxi0 = nxi0; fxr1 = nxr1; fxi1 = nxi1;
        fhr  = nhr;  fhi  = nhi;
    }

    // epilogue: D col = cc, row = (reg&3) + 8*(reg>>2) + 4*half
    float2* __restrict__ op0 = out;
    float2* __restrict__ op1 = out + (size_t)NOUT;
    #pragma unroll
    for (int v = 0; v < 16; ++v) {
        int row = (v & 3) + 8 * (v >> 2) + 4 * half;
        int n = nw + 32 * row + cc;
        if (n < NOUT) {
            op0[n] = make_float2(acc_re0[v], acc_im0[v]);
            op1[n] = make_float2(acc_re1[v], acc_im1[v]);
        }
    }
}

__global__ __launch_bounds__(BLK, 2)
void fir_stag(const float* __restrict__ txr_all, const float* __restrict__ txi_all,
              const short* __restrict__ hh, float2* __restrict__ out) {
    const int bid  = blockIdx.x;
    const int tid  = threadIdx.x;
    const int lane = tid & 63;
    const int wave = tid >> 6;

    // double-buffered x: [buf][0]=xr p0,[1]=xi p0,[2]=xr p1,[3]=xi p1 (74 KB)
    __shared__ __align__(16) short xs[2][4][XSZ];

    const int t0 = bid;
    const int t1 = bid + GRID;
    // stagger bit: bid k and k+256 (the plausible CU pair) get opposite phase
    const bool stagger = (bid >> 8) & 1;

    if (stagger) {
        stage_tile(txr_all, txi_all, xs[0], t0, tid);
        stage_tile(txr_all, txi_all, xs[1], t1, tid);
        BAR();
        compute_tile(hh, out, &xs[0][0][0], t0, lane, wave);
        compute_tile(hh, out, &xs[1][0][0], t1, lane, wave);
    } else {
        stage_tile(txr_all, txi_all, xs[0], t0, tid);
        BAR();
        compute_tile(hh, out, &xs[0][0][0], t0, lane, wave);
        stage_tile(txr_all, txi_all, xs[1], t1, tid);
        BAR();
        compute_tile(hh, out, &xs[1][0][0], t1, lane, wave);
    }

    if (bid == GRID - 1) {   // runt tile (512 outputs past the last full tile)
        BAR();               // all waves done reading xs[0]
        stage_tile(txr_all, txi_all, xs[0], RUNT, tid);
        BAR();
        compute_tile(hh, out, &xs[0][0][0], RUNT, lane, wave);
    }
}

extern "C" void kernel_launch(void* const* d_in, const int* in_sizes, int n_in,
                              void* d_out, int out_size, void* d_ws, size_t ws_size,
                              hipStream_t stream) {
    const float* txr = (const float*)d_in[0];
    const float* txi = (const float*)d_in[1];
    const float* hr  = (const float*)d_in[2];
    const float* hi  = (const float*)d_in[3];
    float2* out = (float2*)d_out;
    short* hh = (short*)d_ws;   // 2 * 592 * 8 bf16 ≈ 19 KB

    build_h<<<dim3((HROWS + BLK - 1) / BLK), BLK, 0, stream>>>(hr, hi, hh);

    fir_stag<<<dim3(GRID), BLK, 0, stream>>>(txr, txi, hh, out);
}